// Round 4
// baseline (1080.210 us; speedup 1.0000x reference)
//
#include <hip/hip_runtime.h>
#include <hip/hip_bf16.h>
#include <math.h>

#define NDIS 20000
#define NSYN 8000
#define NTCM 4000
#define DIM  128
#define NSYMV 4
#define BB   64
#define NE1  400000
#define NE2  200000
#define DSN  (NDIS + NSYN)   // 28000
#define STN  (NSYN + NTCM)   // 12000

// fixed-point scales for deterministic (order-independent) accumulation
#define PROP_S    4194304.0f        // 2^22
#define PROP_INVS (1.0f / 4194304.0f)
#define BSYM_S    16777216.0f       // 2^24
#define BSYM_INVS (1.0f / 16777216.0f)

// ---------------- CSR build ----------------

__global__ void count_edges(const int* __restrict__ src, const int* __restrict__ dst,
                            int E, int n_src, int* __restrict__ cnt) {
    int i = blockIdx.x * blockDim.x + threadIdx.x;
    if (i < E) {
        atomicAdd(&cnt[src[i]], 1);
        atomicAdd(&cnt[dst[i] + n_src], 1);
    }
}

// single-block scan, wave-shuffle based
__global__ __launch_bounds__(1024) void scan_offsets(const int* __restrict__ cnt,
                                                     int* __restrict__ off,
                                                     int* __restrict__ cursor, int N) {
    __shared__ int wsum[16];
    __shared__ int carry_s;
    int tid = threadIdx.x;
    int lane = tid & 63, w = tid >> 6;
    if (tid == 0) carry_s = 0;
    __syncthreads();
    for (int base = 0; base < N; base += 1024) {
        int i = base + tid;
        int v = (i < N) ? cnt[i] : 0;
        int x = v;
#pragma unroll
        for (int d = 1; d < 64; d <<= 1) {
            int t = __shfl_up(x, d);
            if (lane >= d) x += t;
        }
        if (lane == 63) wsum[w] = x;
        __syncthreads();
        if (w == 0) {
            int y = (lane < 16) ? wsum[lane] : 0;
#pragma unroll
            for (int d = 1; d < 16; d <<= 1) {
                int t = __shfl_up(y, d);
                if (lane >= d) y += t;
            }
            if (lane < 16) wsum[lane] = y;
        }
        __syncthreads();
        int carry = carry_s;
        int wpre = (w > 0) ? wsum[w - 1] : 0;
        int excl = carry + wpre + x - v;
        if (i < N) { off[i] = excl; cursor[i] = excl; }
        __syncthreads();
        if (tid == 1023) carry_s = carry + wsum[15];
        __syncthreads();
    }
    if (tid == 0) off[N] = carry_s;
}

__global__ void compute_dinv(const int* __restrict__ cnt, float* __restrict__ dinv, int N) {
    int i = blockIdx.x * blockDim.x + threadIdx.x;
    if (i < N) {
        int c = cnt[i];
        dinv[i] = (c > 0) ? 1.0f / sqrtf((float)c) : 0.0f;
    }
}

__global__ void fill_csr(const int* __restrict__ src, const int* __restrict__ dst,
                         int E, int n_src, int* __restrict__ cursor, int* __restrict__ col) {
    int i = blockIdx.x * blockDim.x + threadIdx.x;
    if (i < E) {
        int a = src[i], b = dst[i] + n_src;
        int p = atomicAdd(&cursor[a], 1);
        col[p] = b;
        int q = atomicAdd(&cursor[b], 1);
        col[q] = a;
    }
}

// ---------------- e0 = X @ W + bias + emb ----------------

__global__ __launch_bounds__(256) void gemm_e0(
    const float* __restrict__ X, const float* __restrict__ W,
    const float* __restrict__ bias, const float* __restrict__ emb,
    float* __restrict__ out_acc, float* __restrict__ out_ek,
    int N, int F, int vec4, int write_acc)
{
    __shared__ float As[64][36];   // pad 36: rows 16B-aligned for b128 reads
    __shared__ float Bs[32][128];
    const int tid = threadIdx.x;
    const int row0 = blockIdx.x * 64;
    const int tc = tid & 31;
    const int tr = tid >> 5;
    float acc[8][4];
#pragma unroll
    for (int i = 0; i < 8; ++i)
#pragma unroll
        for (int j = 0; j < 4; ++j) acc[i][j] = 0.f;

    for (int k0 = 0; k0 < F; k0 += 32) {
        {   // A tile 64x32
            int ar = tid >> 3;
            int ac = (tid & 7) * 4;
#pragma unroll
            for (int h = 0; h < 2; ++h) {
                int r = ar + h * 32;
                int gr = row0 + r;
                if (vec4) {
                    float4 v = make_float4(0.f, 0.f, 0.f, 0.f);
                    if (gr < N) v = *(const float4*)&X[(long)gr * F + k0 + ac];
                    *(float4*)&As[r][ac] = v;
                } else {
#pragma unroll
                    for (int j = 0; j < 4; ++j) {
                        int k = k0 + ac + j;
                        As[r][ac + j] = (gr < N && k < F) ? X[(long)gr * F + k] : 0.f;
                    }
                }
            }
        }
        {   // B tile 32x128
            int brow = tid >> 5;
            int bc = (tid & 31) * 4;
#pragma unroll
            for (int h = 0; h < 4; ++h) {
                int r = brow + h * 8;
                int k = k0 + r;
                float4 v = make_float4(0.f, 0.f, 0.f, 0.f);
                if (k < F) v = *(const float4*)&W[(long)k * DIM + bc];
                *(float4*)&Bs[r][bc] = v;
            }
        }
        __syncthreads();
#pragma unroll
        for (int kk = 0; kk < 32; kk += 4) {
            float4 a4[8];
#pragma unroll
            for (int i = 0; i < 8; ++i) a4[i] = *(const float4*)&As[tr * 8 + i][kk];
            float4 b0 = *(const float4*)&Bs[kk + 0][tc * 4];
            float4 b1 = *(const float4*)&Bs[kk + 1][tc * 4];
            float4 b2 = *(const float4*)&Bs[kk + 2][tc * 4];
            float4 b3 = *(const float4*)&Bs[kk + 3][tc * 4];
#pragma unroll
            for (int i = 0; i < 8; ++i) {
                acc[i][0] += a4[i].x * b0.x + a4[i].y * b1.x + a4[i].z * b2.x + a4[i].w * b3.x;
                acc[i][1] += a4[i].x * b0.y + a4[i].y * b1.y + a4[i].z * b2.y + a4[i].w * b3.y;
                acc[i][2] += a4[i].x * b0.z + a4[i].y * b1.z + a4[i].z * b2.z + a4[i].w * b3.z;
                acc[i][3] += a4[i].x * b0.w + a4[i].y * b1.w + a4[i].z * b2.w + a4[i].w * b3.w;
            }
        }
        __syncthreads();
    }
#pragma unroll
    for (int i = 0; i < 8; ++i) {
        int r = row0 + tr * 8 + i;
        if (r < N) {
            int c = tc * 4;
            float4 e = *(const float4*)&emb[(long)r * DIM + c];
            float4 bi = *(const float4*)&bias[c];
            float4 v;
            v.x = acc[i][0] + bi.x + e.x;
            v.y = acc[i][1] + bi.y + e.y;
            v.z = acc[i][2] + bi.z + e.z;
            v.w = acc[i][3] + bi.w + e.w;
            if (write_acc) *(float4*)&out_acc[(long)r * DIM + c] = v;
            *(float4*)&out_ek[(long)r * DIM + c] = v;
        }
    }
}

// ---------------- LightGCN propagation: gather per node (wave per node) ----------------
// Deterministic: per-term fixed-point quantization -> integer sum is
// order-independent, so the nondeterministic CSR fill order doesn't matter.

__global__ __launch_bounds__(256) void prop_step(
    const int* __restrict__ off, const int* __restrict__ col,
    const float* __restrict__ dinv, const float* __restrict__ ek,
    float* __restrict__ ek2, float* __restrict__ acc,
    int n0, int n1, int acc_lo, int acc_hi, int ek_lo, int ek_hi)
{
    int wid = n0 + ((blockIdx.x * blockDim.x + threadIdx.x) >> 6);
    int lane = threadIdx.x & 63;
    if (wid >= n1) return;
    int beg = off[wid], end = off[wid + 1];
    float dn = dinv[wid];
    long long sx = 0, sy = 0;
    int j = beg;
    for (; j + 4 <= end; j += 4) {
        int c0 = col[j + 0], c1 = col[j + 1], c2 = col[j + 2], c3 = col[j + 3];
        float w0 = dinv[c0] * PROP_S, w1 = dinv[c1] * PROP_S;
        float w2 = dinv[c2] * PROP_S, w3 = dinv[c3] * PROP_S;
        float2 v0 = *(const float2*)&ek[(long)c0 * DIM + lane * 2];
        float2 v1 = *(const float2*)&ek[(long)c1 * DIM + lane * 2];
        float2 v2 = *(const float2*)&ek[(long)c2 * DIM + lane * 2];
        float2 v3 = *(const float2*)&ek[(long)c3 * DIM + lane * 2];
        sx += (long long)__float2int_rn(w0 * v0.x) + (long long)__float2int_rn(w1 * v1.x)
            + (long long)__float2int_rn(w2 * v2.x) + (long long)__float2int_rn(w3 * v3.x);
        sy += (long long)__float2int_rn(w0 * v0.y) + (long long)__float2int_rn(w1 * v1.y)
            + (long long)__float2int_rn(w2 * v2.y) + (long long)__float2int_rn(w3 * v3.y);
    }
    for (; j < end; ++j) {
        int c = col[j];
        float w = dinv[c] * PROP_S;
        float2 v = *(const float2*)&ek[(long)c * DIM + lane * 2];
        sx += (long long)__float2int_rn(w * v.x);
        sy += (long long)__float2int_rn(w * v.y);
    }
    float ax = (float)sx * PROP_INVS * dn;
    float ay = (float)sy * PROP_INVS * dn;
    if (wid >= ek_lo && wid < ek_hi) {
        float2* e2p = (float2*)&ek2[(long)wid * DIM + lane * 2];
        e2p->x = ax; e2p->y = ay;
    }
    if (wid >= acc_lo && wid < acc_hi) {
        float2* ap = (float2*)&acc[(long)wid * DIM + lane * 2];
        float2 o = *ap;
        o.x += ax; o.y += ay;
        *ap = o;
    }
}

// ---------------- gate + des + fused scores ----------------
// des[s,n,:] = (z/3) * sigmoid((zraw@Wg[s])/3 + bg[s]);  scores[s,n] = des . att

__global__ __launch_bounds__(256) void gate_gemm(
    const float* __restrict__ X, const float* __restrict__ Wg,
    const float* __restrict__ bg, const float* __restrict__ att,
    float* __restrict__ des, float* __restrict__ scores)
{
    const float INV3 = 1.0f / 3.0f;
    int s = blockIdx.y;
    const float* Wm = Wg + (long)s * DIM * DIM;
    __shared__ float As[64][36];
    __shared__ float Bs[32][128];
    const int tid = threadIdx.x;
    const int row0 = blockIdx.x * 64;
    const int tc = tid & 31;
    const int tr = tid >> 5;
    float acc[8][4];
#pragma unroll
    for (int i = 0; i < 8; ++i)
#pragma unroll
        for (int j = 0; j < 4; ++j) acc[i][j] = 0.f;

    for (int k0 = 0; k0 < DIM; k0 += 32) {
        {
            int ar = tid >> 3;
            int ac = (tid & 7) * 4;
#pragma unroll
            for (int h = 0; h < 2; ++h) {
                int r = ar + h * 32;
                int gr = row0 + r;
                float4 v = make_float4(0.f, 0.f, 0.f, 0.f);
                if (gr < NDIS) v = *(const float4*)&X[(long)gr * DIM + k0 + ac];
                *(float4*)&As[r][ac] = v;
            }
        }
        {
            int brow = tid >> 5;
            int bc = (tid & 31) * 4;
#pragma unroll
            for (int h = 0; h < 4; ++h) {
                int r = brow + h * 8;
                *(float4*)&Bs[r][bc] = *(const float4*)&Wm[(long)(k0 + r) * DIM + bc];
            }
        }
        __syncthreads();
#pragma unroll
        for (int kk = 0; kk < 32; kk += 4) {
            float4 a4[8];
#pragma unroll
            for (int i = 0; i < 8; ++i) a4[i] = *(const float4*)&As[tr * 8 + i][kk];
            float4 b0 = *(const float4*)&Bs[kk + 0][tc * 4];
            float4 b1 = *(const float4*)&Bs[kk + 1][tc * 4];
            float4 b2 = *(const float4*)&Bs[kk + 2][tc * 4];
            float4 b3 = *(const float4*)&Bs[kk + 3][tc * 4];
#pragma unroll
            for (int i = 0; i < 8; ++i) {
                acc[i][0] += a4[i].x * b0.x + a4[i].y * b1.x + a4[i].z * b2.x + a4[i].w * b3.x;
                acc[i][1] += a4[i].x * b0.y + a4[i].y * b1.y + a4[i].z * b2.y + a4[i].w * b3.y;
                acc[i][2] += a4[i].x * b0.z + a4[i].y * b1.z + a4[i].z * b2.z + a4[i].w * b3.z;
                acc[i][3] += a4[i].x * b0.w + a4[i].y * b1.w + a4[i].z * b2.w + a4[i].w * b3.w;
            }
        }
        __syncthreads();
    }
    int c = tc * 4;
    float4 av = *(const float4*)&att[c];
    float4 bi = *(const float4*)&bg[s * DIM + c];
#pragma unroll
    for (int i = 0; i < 8; ++i) {
        int r = row0 + tr * 8 + i;
        float4 v = make_float4(0.f, 0.f, 0.f, 0.f);
        if (r < NDIS) {
            float4 z = *(const float4*)&X[(long)r * DIM + c];
            v.x = z.x * INV3 / (1.0f + expf(-(acc[i][0] * INV3 + bi.x)));
            v.y = z.y * INV3 / (1.0f + expf(-(acc[i][1] * INV3 + bi.y)));
            v.z = z.z * INV3 / (1.0f + expf(-(acc[i][2] * INV3 + bi.z)));
            v.w = z.w * INV3 / (1.0f + expf(-(acc[i][3] * INV3 + bi.w)));
            *(float4*)&des[((long)s * NDIS + r) * DIM + c] = v;
        }
        // fused score: dot(des_row, att) reduced across the 32 tc lanes (half-wave)
        float sd = v.x * av.x + v.y * av.y + v.z * av.z + v.w * av.w;
#pragma unroll
        for (int o2 = 1; o2 < 32; o2 <<= 1) sd += __shfl_xor(sd, o2);
        if (tc == 0 && r < NDIS) scores[(long)s * NDIS + r] = sd;
    }
}

// ---------------- masked softmax stats per b (all 4 views in one pass) ----------------

__global__ __launch_bounds__(256) void softmax_stats(
    const float* __restrict__ scores, const int* __restrict__ dm,
    float* __restrict__ m_out, float* __restrict__ z_out)
{
    int b = blockIdx.x, tid = threadIdx.x;
    const int* mk = dm + (long)b * NDIS;
    __shared__ float red[NSYMV][256];
    float mloc[NSYMV] = {-1e9f, -1e9f, -1e9f, -1e9f};
    for (int n = tid; n < NDIS; n += 256) {
        if (mk[n]) {
#pragma unroll
            for (int s = 0; s < NSYMV; ++s)
                mloc[s] = fmaxf(mloc[s], scores[(long)s * NDIS + n]);
        }
    }
#pragma unroll
    for (int s = 0; s < NSYMV; ++s) red[s][tid] = mloc[s];
    __syncthreads();
    for (int o = 128; o; o >>= 1) {
        if (tid < o) {
#pragma unroll
            for (int s = 0; s < NSYMV; ++s)
                red[s][tid] = fmaxf(red[s][tid], red[s][tid + o]);
        }
        __syncthreads();
    }
    float m[NSYMV];
#pragma unroll
    for (int s = 0; s < NSYMV; ++s) m[s] = red[s][0];
    __syncthreads();
    float zloc[NSYMV] = {0.f, 0.f, 0.f, 0.f};
    for (int n = tid; n < NDIS; n += 256) {
        if (mk[n]) {
#pragma unroll
            for (int s = 0; s < NSYMV; ++s)
                zloc[s] += expf(scores[(long)s * NDIS + n] - m[s]);
        }
    }
#pragma unroll
    for (int s = 0; s < NSYMV; ++s) red[s][tid] = zloc[s];
    __syncthreads();
    for (int o = 128; o; o >>= 1) {
        if (tid < o) {
#pragma unroll
            for (int s = 0; s < NSYMV; ++s)
                red[s][tid] += red[s][tid + o];
        }
        __syncthreads();
    }
    if (tid < NSYMV) {
        m_out[b * NSYMV + tid] = m[tid];
        z_out[b * NSYMV + tid] = red[tid][0];
    }
}

// ---------------- b_sym accumulation: per (s, 64-row chunk), all 64 b ----------------
// Deterministic: integer atomics (commutative-exact).

__global__ __launch_bounds__(256) void bsym_kernel(
    const float* __restrict__ des, const float* __restrict__ scores,
    const int* __restrict__ dm, const float* __restrict__ m_in,
    const float* __restrict__ z_in, int* __restrict__ b_sym_i)
{
    int s = blockIdx.y;
    int n0 = blockIdx.x * 64;
    int tid = threadIdx.x;
    __shared__ float desS[64][128];
    __shared__ float wS[64][65];   // [b][n']
#pragma unroll
    for (int i = 0; i < 8; ++i) {
        int idx = i * 256 + tid;           // float4 index over 64*32
        int r = idx >> 5, c4 = (idx & 31) * 4;
        int n = n0 + r;
        float4 v = make_float4(0.f, 0.f, 0.f, 0.f);
        if (n < NDIS) v = *(const float4*)&des[((long)s * NDIS + n) * DIM + c4];
        *(float4*)&desS[r][c4] = v;
    }
    {
        int b = tid >> 2;
        int q = tid & 3;
        float m = m_in[b * NSYMV + s];
        float Z = z_in[b * NSYMV + s];
#pragma unroll
        for (int h = 0; h < 16; ++h) {
            int nn = q * 16 + h;
            int n = n0 + nn;
            float w = 0.f;
            if (n < NDIS && dm[(long)b * NDIS + n])
                w = expf(scores[(long)s * NDIS + n] - m) / Z;
            wS[b][nn] = w;
        }
    }
    __syncthreads();
    const int tb = tid & 7;
    const int td = tid >> 3;
    float acc[8][4];
#pragma unroll
    for (int i = 0; i < 8; ++i)
#pragma unroll
        for (int j = 0; j < 4; ++j) acc[i][j] = 0.f;
    for (int nn = 0; nn < 64; ++nn) {
        float4 dv = *(const float4*)&desS[nn][td * 4];
#pragma unroll
        for (int i = 0; i < 8; ++i) {
            float w = wS[tb * 8 + i][nn];
            acc[i][0] += w * dv.x; acc[i][1] += w * dv.y;
            acc[i][2] += w * dv.z; acc[i][3] += w * dv.w;
        }
    }
#pragma unroll
    for (int i = 0; i < 8; ++i) {
        int b = tb * 8 + i;
        int c = td * 4;
        int* dst = &b_sym_i[((long)b * NSYMV + s) * DIM + c];
        atomicAdd(dst + 0, __float2int_rn(acc[i][0] * BSYM_S));
        atomicAdd(dst + 1, __float2int_rn(acc[i][1] * BSYM_S));
        atomicAdd(dst + 2, __float2int_rn(acc[i][2] * BSYM_S));
        atomicAdd(dst + 3, __float2int_rn(acc[i][3] * BSYM_S));
    }
}

// ---------------- tiny head: v->o->sym_syn->a2->syn_out, block per b, (s,d) parallel ----------------

__global__ __launch_bounds__(512) void head_kernel(
    const int* __restrict__ b_sym_i,
    const float* __restrict__ Wv, const float* __restrict__ bv,
    const float* __restrict__ Wo, const float* __restrict__ bo,
    const float* __restrict__ Wl, const float* __restrict__ bl,
    const float* __restrict__ symW, const float* __restrict__ symb,
    const float* __restrict__ symu, float* __restrict__ syn_out)
{
    int b = blockIdx.x;
    int tid = threadIdx.x;
    int s = tid >> 7;
    int d = tid & 127;
    __shared__ float xS[NSYMV][DIM];
    __shared__ float yS[NSYMV][DIM];
    __shared__ float red[NSYMV][DIM];
    xS[s][d] = (float)b_sym_i[((long)b * NSYMV + s) * DIM + d] * BSYM_INVS;
    __syncthreads();
    // v = b_sym @ Wv + bv
    float a = bv[d];
    for (int e = 0; e < DIM; ++e) a += xS[s][e] * Wv[e * DIM + d];
    yS[s][d] = a;
    __syncthreads();
    // o = v @ Wo + bo
    a = bo[d];
    for (int e = 0; e < DIM; ++e) a += yS[s][e] * Wo[e * DIM + d];
    xS[s][d] = a;
    __syncthreads();
    // sym_syn = o + o @ Wl[s] + bl[s]
    a = xS[s][d] + bl[s * DIM + d];
    {
        const float* Wls = Wl + (long)s * DIM * DIM;
        for (int e = 0; e < DIM; ++e) a += xS[s][e] * Wls[e * DIM + d];
    }
    yS[s][d] = a;
    __syncthreads();
    // e2 = tanh(sym_syn @ symW + symb) . symu
    a = symb[d];
    for (int e = 0; e < DIM; ++e) a += yS[s][e] * symW[e * DIM + d];
    red[s][d] = tanhf(a) * symu[d];
    __syncthreads();
    for (int o = 64; o; o >>= 1) {
        if (d < o) red[s][d] += red[s][d + o];
        __syncthreads();
    }
    if (tid < DIM) {
        float e0 = red[0][0], e1 = red[1][0], e2v = red[2][0], e3 = red[3][0];
        float m = fmaxf(fmaxf(e0, e1), fmaxf(e2v, e3));
        float a0 = expf(e0 - m), a1 = expf(e1 - m), a2 = expf(e2v - m), a3 = expf(e3 - m);
        float z = a0 + a1 + a2 + a3;
        float o = (a0 * yS[0][d] + a1 * yS[1][d] + a2 * yS[2][d] + a3 * yS[3][d]) / z;
        syn_out[b * DIM + d] = o;
    }
}

// ---------------- out = syn_out @ (z_tcm_raw/3)^T ----------------

__global__ __launch_bounds__(256) void final_gemm(
    const float* __restrict__ syn_o, const float* __restrict__ z_tcm,
    float* __restrict__ out)
{
    const float INV3 = 1.0f / 3.0f;
    int t0 = blockIdx.x * 64;
    int b0 = blockIdx.y * 16;
    int tid = threadIdx.x;
    __shared__ float zS[64][129];
    __shared__ float sS[16][129];
#pragma unroll
    for (int i = 0; i < 8; ++i) {
        int idx = i * 256 + tid;
        int r = idx >> 5, c4 = (idx & 31) * 4;
        int t = t0 + r;
        float4 v = make_float4(0.f, 0.f, 0.f, 0.f);
        if (t < NTCM) v = *(const float4*)&z_tcm[(long)t * DIM + c4];
        zS[r][c4 + 0] = v.x * INV3; zS[r][c4 + 1] = v.y * INV3;
        zS[r][c4 + 2] = v.z * INV3; zS[r][c4 + 3] = v.w * INV3;
    }
#pragma unroll
    for (int i = 0; i < 2; ++i) {
        int idx = i * 256 + tid;           // float4 idx over 16*32
        int r = idx >> 5, c4 = (idx & 31) * 4;
        float4 v = *(const float4*)&syn_o[(long)(b0 + r) * DIM + c4];
        sS[r][c4 + 0] = v.x; sS[r][c4 + 1] = v.y;
        sS[r][c4 + 2] = v.z; sS[r][c4 + 3] = v.w;
    }
    __syncthreads();
    int tt = tid & 63;
    int tbg = tid >> 6;
    float acc4[4] = {0.f, 0.f, 0.f, 0.f};
    for (int dd = 0; dd < DIM; ++dd) {
        float zv = zS[tt][dd];
#pragma unroll
        for (int i = 0; i < 4; ++i) acc4[i] += sS[tbg * 4 + i][dd] * zv;
    }
    int t = t0 + tt;
    if (t < NTCM) {
#pragma unroll
        for (int i = 0; i < 4; ++i)
            out[(long)(b0 + tbg * 4 + i) * NTCM + t] = acc4[i];
    }
}

// ---------------- launch ----------------

extern "C" void kernel_launch(void* const* d_in, const int* in_sizes, int n_in,
                              void* d_out, int out_size, void* d_ws, size_t ws_size,
                              hipStream_t stream)
{
    const float* x_dis  = (const float*)d_in[0];
    const float* x_syn  = (const float*)d_in[1];
    const float* x_tcm  = (const float*)d_in[2];
    const float* ds_Wsf = (const float*)d_in[3];
    const float* ds_bsf = (const float*)d_in[4];
    const float* ds_Wdf = (const float*)d_in[5];
    const float* ds_bdf = (const float*)d_in[6];
    const float* ds_semb = (const float*)d_in[7];
    const float* ds_demb = (const float*)d_in[8];
    const float* st_Wsf = (const float*)d_in[9];
    const float* st_bsf = (const float*)d_in[10];
    const float* st_Wdf = (const float*)d_in[11];
    const float* st_bdf = (const float*)d_in[12];
    const float* st_semb = (const float*)d_in[13];
    const float* st_demb = (const float*)d_in[14];
    const float* Wg  = (const float*)d_in[15];
    const float* bg  = (const float*)d_in[16];
    const float* att = (const float*)d_in[17];
    // d_in[18..20] (syn_W/b/u) and d_in[35] (syn_mask): dead code in reference
    const float* symW = (const float*)d_in[21];
    const float* symb = (const float*)d_in[22];
    const float* symu = (const float*)d_in[23];
    const float* Wv = (const float*)d_in[24];
    const float* bv = (const float*)d_in[25];
    const float* Wo = (const float*)d_in[26];
    const float* bo = (const float*)d_in[27];
    const float* Wl = (const float*)d_in[28];
    const float* bl = (const float*)d_in[29];
    const int* e_ds_src = (const int*)d_in[30];
    const int* e_ds_dst = (const int*)d_in[31];
    const int* e_st_src = (const int*)d_in[32];
    const int* e_st_dst = (const int*)d_in[33];
    const int* dis_mask = (const int*)d_in[34];

    char* p = (char*)d_ws;
    auto alloc = [&](size_t bytes) { char* r = p; p += (bytes + 255) & ~(size_t)255; return (void*)r; };

    // Region A: ek buffers for both graphs; 40,960,000 B == size of des,
    // so des reuses it after propagation.
    float* regA   = (float*)alloc((size_t)(2 * DSN + 2 * STN) * DIM * 4);
    float* ds_ek  = regA;
    float* ds_ek2 = regA + (long)DSN * DIM;
    float* st_ek  = regA + (long)2 * DSN * DIM;
    float* st_ek2 = regA + (long)2 * DSN * DIM + (long)STN * DIM;
    float* des    = regA;

    float* ds_acc = (float*)alloc((size_t)DSN * DIM * 4);
    float* st_acc = (float*)alloc((size_t)STN * DIM * 4);
    float* scores = (float*)alloc((size_t)NSYMV * NDIS * 4);
    int* ds_cnt = (int*)alloc((DSN + 1) * 4);
    int* ds_off = (int*)alloc((DSN + 1) * 4);
    int* ds_cur = (int*)alloc((DSN + 1) * 4);
    int* st_cnt = (int*)alloc((STN + 1) * 4);
    int* st_off = (int*)alloc((STN + 1) * 4);
    int* st_cur = (int*)alloc((STN + 1) * 4);
    float* ds_dinv = (float*)alloc(DSN * 4);
    float* st_dinv = (float*)alloc(STN * 4);
    int* ds_col = (int*)alloc((size_t)2 * NE1 * 4);
    int* st_col = (int*)alloc((size_t)2 * NE2 * 4);
    float* m_bs = (float*)alloc(BB * NSYMV * 4);
    float* z_bs = (float*)alloc(BB * NSYMV * 4);
    int* b_sym_i = (int*)alloc((size_t)BB * NSYMV * DIM * 4);
    float* syn_o = (float*)alloc((size_t)BB * DIM * 4);

    // --- CSR build for both graphs ---
    hipMemsetAsync(ds_cnt, 0, DSN * 4, stream);
    hipMemsetAsync(st_cnt, 0, STN * 4, stream);
    count_edges<<<(NE1 + 255) / 256, 256, 0, stream>>>(e_ds_src, e_ds_dst, NE1, NDIS, ds_cnt);
    count_edges<<<(NE2 + 255) / 256, 256, 0, stream>>>(e_st_src, e_st_dst, NE2, NSYN, st_cnt);
    scan_offsets<<<1, 1024, 0, stream>>>(ds_cnt, ds_off, ds_cur, DSN);
    scan_offsets<<<1, 1024, 0, stream>>>(st_cnt, st_off, st_cur, STN);
    compute_dinv<<<(DSN + 255) / 256, 256, 0, stream>>>(ds_cnt, ds_dinv, DSN);
    compute_dinv<<<(STN + 255) / 256, 256, 0, stream>>>(st_cnt, st_dinv, STN);
    fill_csr<<<(NE1 + 255) / 256, 256, 0, stream>>>(e_ds_src, e_ds_dst, NE1, NDIS, ds_cur, ds_col);
    fill_csr<<<(NE2 + 255) / 256, 256, 0, stream>>>(e_st_src, e_st_dst, NE2, NSYN, st_cur, st_col);

    // --- e0 GEMMs (fused bias+emb; acc write skipped for dead halves) ---
    gemm_e0<<<dim3((NDIS + 63) / 64), 256, 0, stream>>>(x_dis, ds_Wsf, ds_bsf, ds_semb,
        ds_acc, ds_ek, NDIS, 384, 1, 1);
    gemm_e0<<<dim3((NSYN + 63) / 64), 256, 0, stream>>>(x_syn, ds_Wdf, ds_bdf, ds_demb,
        ds_acc + (long)NDIS * DIM, ds_ek + (long)NDIS * DIM, NSYN, 256, 1, 0);
    gemm_e0<<<dim3((NSYN + 63) / 64), 256, 0, stream>>>(x_syn, st_Wsf, st_bsf, st_semb,
        st_acc, st_ek, NSYN, 256, 1, 0);
    gemm_e0<<<dim3((NTCM + 63) / 64), 256, 0, stream>>>(x_tcm, st_Wdf, st_bdf, st_demb,
        st_acc + (long)NSYN * DIM, st_ek + (long)NSYN * DIM, NTCM, 103, 0, 1);

    // --- K=2 propagation (gather; only live node ranges; deterministic int accum) ---
    // ds step1: all nodes; acc for dis [0,NDIS); ek2 only for syn [NDIS,DSN)
    prop_step<<<(DSN + 3) / 4, 256, 0, stream>>>(ds_off, ds_col, ds_dinv, ds_ek, ds_ek2, ds_acc,
                                                 0, DSN, 0, NDIS, NDIS, DSN);
    // ds step2: dis nodes only; acc for dis; no ek2
    prop_step<<<(NDIS + 3) / 4, 256, 0, stream>>>(ds_off, ds_col, ds_dinv, ds_ek2, ds_ek, ds_acc,
                                                  0, NDIS, 0, NDIS, 0, 0);
    // st step1: all nodes; acc for tcm [NSYN,STN); ek2 only for syn [0,NSYN)
    prop_step<<<(STN + 3) / 4, 256, 0, stream>>>(st_off, st_col, st_dinv, st_ek, st_ek2, st_acc,
                                                 0, STN, NSYN, STN, 0, NSYN);
    // st step2: tcm nodes only; acc for tcm; no ek2
    prop_step<<<(NTCM + 3) / 4, 256, 0, stream>>>(st_off, st_col, st_dinv, st_ek2, st_ek, st_acc,
                                                  NSYN, STN, NSYN, STN, 0, 0);

    const float* z_dis_raw = ds_acc;                       // = 3*z_dis, scaled in consumers
    const float* z_tcm_raw = st_acc + (long)NSYN * DIM;    // = 3*z_tcm

    // --- gate/des + fused scores (overwrites region A: ek buffers dead now) ---
    gate_gemm<<<dim3((NDIS + 63) / 64, NSYMV), 256, 0, stream>>>(z_dis_raw, Wg, bg, att, des, scores);
    softmax_stats<<<BB, 256, 0, stream>>>(scores, dis_mask, m_bs, z_bs);
    hipMemsetAsync(b_sym_i, 0, (size_t)BB * NSYMV * DIM * 4, stream);
    bsym_kernel<<<dim3((NDIS + 63) / 64, NSYMV), 256, 0, stream>>>(des, scores, dis_mask, m_bs, z_bs, b_sym_i);
    head_kernel<<<BB, 512, 0, stream>>>(b_sym_i, Wv, bv, Wo, bo, Wl, bl, symW, symb, symu, syn_o);
    final_gemm<<<dim3((NTCM + 63) / 64, BB / 16), 256, 0, stream>>>(syn_o, z_tcm_raw, (float*)d_out);
}

// Round 6
// 927.472 us; speedup vs baseline: 1.1647x; 1.1647x over previous
//
#include <hip/hip_runtime.h>
#include <hip/hip_bf16.h>
#include <math.h>

#define NDIS 20000
#define NSYN 8000
#define NTCM 4000
#define DIM  128
#define NSYMV 4
#define BB   64
#define NE1  400000
#define NE2  200000
#define DSN  (NDIS + NSYN)   // 28000
#define STN  (NSYN + NTCM)   // 12000

// b_sym chunking (atomic-free partials). BCHUNK=192 so the partials slab
// (NBCHUNK*4*64*128*4B = 13.76 MB) fits inside the dead ds_acc region (14.34 MB).
#define BCHUNK 192
#define NBCHUNK ((NDIS + BCHUNK - 1) / BCHUNK)   // 105

// fixed-point scale for deterministic (order-independent) prop accumulation
#define PROP_S    4194304.0f        // 2^22
#define PROP_INVS (1.0f / 4194304.0f)

// ---------------- CSR build ----------------

__global__ void count_edges(const int* __restrict__ src, const int* __restrict__ dst,
                            int E, int n_src, int* __restrict__ cnt) {
    int i = blockIdx.x * blockDim.x + threadIdx.x;
    if (i < E) {
        atomicAdd(&cnt[src[i]], 1);
        atomicAdd(&cnt[dst[i] + n_src], 1);
    }
}

// single-block scan, wave-shuffle based
__global__ __launch_bounds__(1024) void scan_offsets(const int* __restrict__ cnt,
                                                     int* __restrict__ off,
                                                     int* __restrict__ cursor, int N) {
    __shared__ int wsum[16];
    __shared__ int carry_s;
    int tid = threadIdx.x;
    int lane = tid & 63, w = tid >> 6;
    if (tid == 0) carry_s = 0;
    __syncthreads();
    for (int base = 0; base < N; base += 1024) {
        int i = base + tid;
        int v = (i < N) ? cnt[i] : 0;
        int x = v;
#pragma unroll
        for (int d = 1; d < 64; d <<= 1) {
            int t = __shfl_up(x, d);
            if (lane >= d) x += t;
        }
        if (lane == 63) wsum[w] = x;
        __syncthreads();
        if (w == 0) {
            int y = (lane < 16) ? wsum[lane] : 0;
#pragma unroll
            for (int d = 1; d < 16; d <<= 1) {
                int t = __shfl_up(y, d);
                if (lane >= d) y += t;
            }
            if (lane < 16) wsum[lane] = y;
        }
        __syncthreads();
        int carry = carry_s;
        int wpre = (w > 0) ? wsum[w - 1] : 0;
        int excl = carry + wpre + x - v;
        if (i < N) { off[i] = excl; cursor[i] = excl; }
        __syncthreads();
        if (tid == 1023) carry_s = carry + wsum[15];
        __syncthreads();
    }
    if (tid == 0) off[N] = carry_s;
}

__global__ void compute_dinv(const int* __restrict__ cnt, float* __restrict__ dinv, int N) {
    int i = blockIdx.x * blockDim.x + threadIdx.x;
    if (i < N) {
        int c = cnt[i];
        dinv[i] = (c > 0) ? 1.0f / sqrtf((float)c) : 0.0f;
    }
}

__global__ void fill_csr(const int* __restrict__ src, const int* __restrict__ dst,
                         int E, int n_src, int* __restrict__ cursor, int* __restrict__ col) {
    int i = blockIdx.x * blockDim.x + threadIdx.x;
    if (i < E) {
        int a = src[i], b = dst[i] + n_src;
        int p = atomicAdd(&cursor[a], 1);
        col[p] = b;
        int q = atomicAdd(&cursor[b], 1);
        col[q] = a;
    }
}

// ---------------- e0 = X @ W + bias + emb ----------------

__global__ __launch_bounds__(256) void gemm_e0(
    const float* __restrict__ X, const float* __restrict__ W,
    const float* __restrict__ bias, const float* __restrict__ emb,
    float* __restrict__ out_acc, float* __restrict__ out_ek,
    int N, int F, int vec4, int write_acc)
{
    __shared__ float As[64][36];   // pad 36: rows 16B-aligned for b128 reads
    __shared__ float Bs[32][128];
    const int tid = threadIdx.x;
    const int row0 = blockIdx.x * 64;
    const int tc = tid & 31;
    const int tr = tid >> 5;
    float acc[8][4];
#pragma unroll
    for (int i = 0; i < 8; ++i)
#pragma unroll
        for (int j = 0; j < 4; ++j) acc[i][j] = 0.f;

    for (int k0 = 0; k0 < F; k0 += 32) {
        {   // A tile 64x32
            int ar = tid >> 3;
            int ac = (tid & 7) * 4;
#pragma unroll
            for (int h = 0; h < 2; ++h) {
                int r = ar + h * 32;
                int gr = row0 + r;
                if (vec4) {
                    float4 v = make_float4(0.f, 0.f, 0.f, 0.f);
                    if (gr < N) v = *(const float4*)&X[(long)gr * F + k0 + ac];
                    *(float4*)&As[r][ac] = v;
                } else {
#pragma unroll
                    for (int j = 0; j < 4; ++j) {
                        int k = k0 + ac + j;
                        As[r][ac + j] = (gr < N && k < F) ? X[(long)gr * F + k] : 0.f;
                    }
                }
            }
        }
        {   // B tile 32x128
            int brow = tid >> 5;
            int bc = (tid & 31) * 4;
#pragma unroll
            for (int h = 0; h < 4; ++h) {
                int r = brow + h * 8;
                int k = k0 + r;
                float4 v = make_float4(0.f, 0.f, 0.f, 0.f);
                if (k < F) v = *(const float4*)&W[(long)k * DIM + bc];
                *(float4*)&Bs[r][bc] = v;
            }
        }
        __syncthreads();
#pragma unroll
        for (int kk = 0; kk < 32; kk += 4) {
            float4 a4[8];
#pragma unroll
            for (int i = 0; i < 8; ++i) a4[i] = *(const float4*)&As[tr * 8 + i][kk];
            float4 b0 = *(const float4*)&Bs[kk + 0][tc * 4];
            float4 b1 = *(const float4*)&Bs[kk + 1][tc * 4];
            float4 b2 = *(const float4*)&Bs[kk + 2][tc * 4];
            float4 b3 = *(const float4*)&Bs[kk + 3][tc * 4];
#pragma unroll
            for (int i = 0; i < 8; ++i) {
                acc[i][0] += a4[i].x * b0.x + a4[i].y * b1.x + a4[i].z * b2.x + a4[i].w * b3.x;
                acc[i][1] += a4[i].x * b0.y + a4[i].y * b1.y + a4[i].z * b2.y + a4[i].w * b3.y;
                acc[i][2] += a4[i].x * b0.z + a4[i].y * b1.z + a4[i].z * b2.z + a4[i].w * b3.z;
                acc[i][3] += a4[i].x * b0.w + a4[i].y * b1.w + a4[i].z * b2.w + a4[i].w * b3.w;
            }
        }
        __syncthreads();
    }
#pragma unroll
    for (int i = 0; i < 8; ++i) {
        int r = row0 + tr * 8 + i;
        if (r < N) {
            int c = tc * 4;
            float4 e = *(const float4*)&emb[(long)r * DIM + c];
            float4 bi = *(const float4*)&bias[c];
            float4 v;
            v.x = acc[i][0] + bi.x + e.x;
            v.y = acc[i][1] + bi.y + e.y;
            v.z = acc[i][2] + bi.z + e.z;
            v.w = acc[i][3] + bi.w + e.w;
            if (write_acc) *(float4*)&out_acc[(long)r * DIM + c] = v;
            *(float4*)&out_ek[(long)r * DIM + c] = v;
        }
    }
}

// ---------------- LightGCN propagation: gather per node (wave per node) ----------------
// Deterministic: per-term fixed-point quantization -> integer sum is
// order-independent, so the nondeterministic CSR fill order doesn't matter.

__global__ __launch_bounds__(256) void prop_step(
    const int* __restrict__ off, const int* __restrict__ col,
    const float* __restrict__ dinv, const float* __restrict__ ek,
    float* __restrict__ ek2, float* __restrict__ acc,
    int n0, int n1, int acc_lo, int acc_hi, int ek_lo, int ek_hi)
{
    int wid = n0 + ((blockIdx.x * blockDim.x + threadIdx.x) >> 6);
    int lane = threadIdx.x & 63;
    if (wid >= n1) return;
    int beg = off[wid], end = off[wid + 1];
    float dn = dinv[wid];
    long long sx = 0, sy = 0;
    int j = beg;
    for (; j + 4 <= end; j += 4) {
        int c0 = col[j + 0], c1 = col[j + 1], c2 = col[j + 2], c3 = col[j + 3];
        float w0 = dinv[c0] * PROP_S, w1 = dinv[c1] * PROP_S;
        float w2 = dinv[c2] * PROP_S, w3 = dinv[c3] * PROP_S;
        float2 v0 = *(const float2*)&ek[(long)c0 * DIM + lane * 2];
        float2 v1 = *(const float2*)&ek[(long)c1 * DIM + lane * 2];
        float2 v2 = *(const float2*)&ek[(long)c2 * DIM + lane * 2];
        float2 v3 = *(const float2*)&ek[(long)c3 * DIM + lane * 2];
        sx += (long long)__float2int_rn(w0 * v0.x) + (long long)__float2int_rn(w1 * v1.x)
            + (long long)__float2int_rn(w2 * v2.x) + (long long)__float2int_rn(w3 * v3.x);
        sy += (long long)__float2int_rn(w0 * v0.y) + (long long)__float2int_rn(w1 * v1.y)
            + (long long)__float2int_rn(w2 * v2.y) + (long long)__float2int_rn(w3 * v3.y);
    }
    for (; j < end; ++j) {
        int c = col[j];
        float w = dinv[c] * PROP_S;
        float2 v = *(const float2*)&ek[(long)c * DIM + lane * 2];
        sx += (long long)__float2int_rn(w * v.x);
        sy += (long long)__float2int_rn(w * v.y);
    }
    float ax = (float)sx * PROP_INVS * dn;
    float ay = (float)sy * PROP_INVS * dn;
    if (wid >= ek_lo && wid < ek_hi) {
        float2* e2p = (float2*)&ek2[(long)wid * DIM + lane * 2];
        e2p->x = ax; e2p->y = ay;
    }
    if (wid >= acc_lo && wid < acc_hi) {
        float2* ap = (float2*)&acc[(long)wid * DIM + lane * 2];
        float2 o = *ap;
        o.x += ax; o.y += ay;
        *ap = o;
    }
}

// ---------------- gate + des + fused scores ----------------
// des[s,n,:] = (z/3) * sigmoid((zraw@Wg[s])/3 + bg[s]);  scores[s,n] = des . att

__global__ __launch_bounds__(256) void gate_gemm(
    const float* __restrict__ X, const float* __restrict__ Wg,
    const float* __restrict__ bg, const float* __restrict__ att,
    float* __restrict__ des, float* __restrict__ scores)
{
    const float INV3 = 1.0f / 3.0f;
    int s = blockIdx.y;
    const float* Wm = Wg + (long)s * DIM * DIM;
    __shared__ float As[64][36];
    __shared__ float Bs[32][128];
    const int tid = threadIdx.x;
    const int row0 = blockIdx.x * 64;
    const int tc = tid & 31;
    const int tr = tid >> 5;
    float acc[8][4];
#pragma unroll
    for (int i = 0; i < 8; ++i)
#pragma unroll
        for (int j = 0; j < 4; ++j) acc[i][j] = 0.f;

    for (int k0 = 0; k0 < DIM; k0 += 32) {
        {
            int ar = tid >> 3;
            int ac = (tid & 7) * 4;
#pragma unroll
            for (int h = 0; h < 2; ++h) {
                int r = ar + h * 32;
                int gr = row0 + r;
                float4 v = make_float4(0.f, 0.f, 0.f, 0.f);
                if (gr < NDIS) v = *(const float4*)&X[(long)gr * DIM + k0 + ac];
                *(float4*)&As[r][ac] = v;
            }
        }
        {
            int brow = tid >> 5;
            int bc = (tid & 31) * 4;
#pragma unroll
            for (int h = 0; h < 4; ++h) {
                int r = brow + h * 8;
                *(float4*)&Bs[r][bc] = *(const float4*)&Wm[(long)(k0 + r) * DIM + bc];
            }
        }
        __syncthreads();
#pragma unroll
        for (int kk = 0; kk < 32; kk += 4) {
            float4 a4[8];
#pragma unroll
            for (int i = 0; i < 8; ++i) a4[i] = *(const float4*)&As[tr * 8 + i][kk];
            float4 b0 = *(const float4*)&Bs[kk + 0][tc * 4];
            float4 b1 = *(const float4*)&Bs[kk + 1][tc * 4];
            float4 b2 = *(const float4*)&Bs[kk + 2][tc * 4];
            float4 b3 = *(const float4*)&Bs[kk + 3][tc * 4];
#pragma unroll
            for (int i = 0; i < 8; ++i) {
                acc[i][0] += a4[i].x * b0.x + a4[i].y * b1.x + a4[i].z * b2.x + a4[i].w * b3.x;
                acc[i][1] += a4[i].x * b0.y + a4[i].y * b1.y + a4[i].z * b2.y + a4[i].w * b3.y;
                acc[i][2] += a4[i].x * b0.z + a4[i].y * b1.z + a4[i].z * b2.z + a4[i].w * b3.z;
                acc[i][3] += a4[i].x * b0.w + a4[i].y * b1.w + a4[i].z * b2.w + a4[i].w * b3.w;
            }
        }
        __syncthreads();
    }
    int c = tc * 4;
    float4 av = *(const float4*)&att[c];
    float4 bi = *(const float4*)&bg[s * DIM + c];
#pragma unroll
    for (int i = 0; i < 8; ++i) {
        int r = row0 + tr * 8 + i;
        float4 v = make_float4(0.f, 0.f, 0.f, 0.f);
        if (r < NDIS) {
            float4 z = *(const float4*)&X[(long)r * DIM + c];
            v.x = z.x * INV3 / (1.0f + expf(-(acc[i][0] * INV3 + bi.x)));
            v.y = z.y * INV3 / (1.0f + expf(-(acc[i][1] * INV3 + bi.y)));
            v.z = z.z * INV3 / (1.0f + expf(-(acc[i][2] * INV3 + bi.z)));
            v.w = z.w * INV3 / (1.0f + expf(-(acc[i][3] * INV3 + bi.w)));
            *(float4*)&des[((long)s * NDIS + r) * DIM + c] = v;
        }
        // fused score: dot(des_row, att) reduced across the 32 tc lanes (half-wave)
        float sd = v.x * av.x + v.y * av.y + v.z * av.z + v.w * av.w;
#pragma unroll
        for (int o2 = 1; o2 < 32; o2 <<= 1) sd += __shfl_xor(sd, o2);
        if (tc == 0 && r < NDIS) scores[(long)s * NDIS + r] = sd;
    }
}

// ---------------- masked softmax stats per b (all 4 views in one pass) ----------------

__global__ __launch_bounds__(256) void softmax_stats(
    const float* __restrict__ scores, const int* __restrict__ dm,
    float* __restrict__ m_out, float* __restrict__ z_out)
{
    int b = blockIdx.x, tid = threadIdx.x;
    const int* mk = dm + (long)b * NDIS;
    __shared__ float red[NSYMV][256];
    float mloc[NSYMV] = {-1e9f, -1e9f, -1e9f, -1e9f};
    for (int n = tid; n < NDIS; n += 256) {
        if (mk[n]) {
#pragma unroll
            for (int s = 0; s < NSYMV; ++s)
                mloc[s] = fmaxf(mloc[s], scores[(long)s * NDIS + n]);
        }
    }
#pragma unroll
    for (int s = 0; s < NSYMV; ++s) red[s][tid] = mloc[s];
    __syncthreads();
    for (int o = 128; o; o >>= 1) {
        if (tid < o) {
#pragma unroll
            for (int s = 0; s < NSYMV; ++s)
                red[s][tid] = fmaxf(red[s][tid], red[s][tid + o]);
        }
        __syncthreads();
    }
    float m[NSYMV];
#pragma unroll
    for (int s = 0; s < NSYMV; ++s) m[s] = red[s][0];
    __syncthreads();
    float zloc[NSYMV] = {0.f, 0.f, 0.f, 0.f};
    for (int n = tid; n < NDIS; n += 256) {
        if (mk[n]) {
#pragma unroll
            for (int s = 0; s < NSYMV; ++s)
                zloc[s] += expf(scores[(long)s * NDIS + n] - m[s]);
        }
    }
#pragma unroll
    for (int s = 0; s < NSYMV; ++s) red[s][tid] = zloc[s];
    __syncthreads();
    for (int o = 128; o; o >>= 1) {
        if (tid < o) {
#pragma unroll
            for (int s = 0; s < NSYMV; ++s)
                red[s][tid] += red[s][tid + o];
        }
        __syncthreads();
    }
    if (tid < NSYMV) {
        m_out[b * NSYMV + tid] = m[tid];
        z_out[b * NSYMV + tid] = red[tid][0];
    }
}

// ---------------- b_sym partials: per (s, BCHUNK-row chunk), all 64 b; NO atomics ----------------
// partials layout: [chunk][s][b][d]

__global__ __launch_bounds__(256) void bsym_partial(
    const float* __restrict__ des, const float* __restrict__ scores,
    const int* __restrict__ dm, const float* __restrict__ m_in,
    const float* __restrict__ z_in, float* __restrict__ partials)
{
    int s = blockIdx.y;
    int chunk = blockIdx.x;
    int tid = threadIdx.x;
    __shared__ float desS[64][128];
    __shared__ float wS[64][65];   // [b][n']
    const int tb = tid & 7;
    const int td = tid >> 3;
    float acc[8][4];
#pragma unroll
    for (int i = 0; i < 8; ++i)
#pragma unroll
        for (int j = 0; j < 4; ++j) acc[i][j] = 0.f;

    for (int sub = 0; sub < BCHUNK / 64; ++sub) {
        int n0 = chunk * BCHUNK + sub * 64;
#pragma unroll
        for (int i = 0; i < 8; ++i) {
            int idx = i * 256 + tid;           // float4 index over 64*32
            int r = idx >> 5, c4 = (idx & 31) * 4;
            int n = n0 + r;
            float4 v = make_float4(0.f, 0.f, 0.f, 0.f);
            if (n < NDIS) v = *(const float4*)&des[((long)s * NDIS + n) * DIM + c4];
            *(float4*)&desS[r][c4] = v;
        }
        {
            int b = tid >> 2;
            int q = tid & 3;
            float m = m_in[b * NSYMV + s];
            float Z = z_in[b * NSYMV + s];
#pragma unroll
            for (int h = 0; h < 16; ++h) {
                int nn = q * 16 + h;
                int n = n0 + nn;
                float w = 0.f;
                if (n < NDIS && dm[(long)b * NDIS + n])
                    w = expf(scores[(long)s * NDIS + n] - m) / Z;
                wS[b][nn] = w;
            }
        }
        __syncthreads();
        for (int nn = 0; nn < 64; ++nn) {
            float4 dv = *(const float4*)&desS[nn][td * 4];
#pragma unroll
            for (int i = 0; i < 8; ++i) {
                float w = wS[tb * 8 + i][nn];
                acc[i][0] += w * dv.x; acc[i][1] += w * dv.y;
                acc[i][2] += w * dv.z; acc[i][3] += w * dv.w;
            }
        }
        __syncthreads();
    }
    float* pp = partials + ((long)chunk * NSYMV + s) * (BB * DIM);
#pragma unroll
    for (int i = 0; i < 8; ++i) {
        int b = tb * 8 + i;
        float4 v;
        v.x = acc[i][0]; v.y = acc[i][1]; v.z = acc[i][2]; v.w = acc[i][3];
        *(float4*)&pp[b * DIM + td * 4] = v;
    }
}

// ---------------- reduce partials over chunks (fixed order -> deterministic) ----------------
// b_sym layout: [s][b][d]

__global__ __launch_bounds__(256) void bsym_reduce(
    const float* __restrict__ partials, float* __restrict__ b_sym)
{
    int o = blockIdx.x * 256 + threadIdx.x;   // over NSYMV*BB*DIM = 32768
    float a = 0.f;
    for (int c = 0; c < NBCHUNK; ++c)
        a += partials[(long)c * (NSYMV * BB * DIM) + o];
    b_sym[o] = a;
}

// ---------------- tiny head: v->o->sym_syn->a2->syn_out, block per b, (s,d) parallel ----------------

__global__ __launch_bounds__(512) void head_kernel(
    const float* __restrict__ b_sym,   // [s][b][d]
    const float* __restrict__ Wv, const float* __restrict__ bv,
    const float* __restrict__ Wo, const float* __restrict__ bo,
    const float* __restrict__ Wl, const float* __restrict__ bl,
    const float* __restrict__ symW, const float* __restrict__ symb,
    const float* __restrict__ symu, float* __restrict__ syn_out)
{
    int b = blockIdx.x;
    int tid = threadIdx.x;
    int s = tid >> 7;
    int d = tid & 127;
    __shared__ float xS[NSYMV][DIM];
    __shared__ float yS[NSYMV][DIM];
    __shared__ float red[NSYMV][DIM];
    xS[s][d] = b_sym[((long)s * BB + b) * DIM + d];
    __syncthreads();
    // v = b_sym @ Wv + bv
    float a = bv[d];
    for (int e = 0; e < DIM; ++e) a += xS[s][e] * Wv[e * DIM + d];
    yS[s][d] = a;
    __syncthreads();
    // o = v @ Wo + bo
    a = bo[d];
    for (int e = 0; e < DIM; ++e) a += yS[s][e] * Wo[e * DIM + d];
    xS[s][d] = a;
    __syncthreads();
    // sym_syn = o + o @ Wl[s] + bl[s]
    a = xS[s][d] + bl[s * DIM + d];
    {
        const float* Wls = Wl + (long)s * DIM * DIM;
        for (int e = 0; e < DIM; ++e) a += xS[s][e] * Wls[e * DIM + d];
    }
    yS[s][d] = a;
    __syncthreads();
    // e2 = tanh(sym_syn @ symW + symb) . symu
    a = symb[d];
    for (int e = 0; e < DIM; ++e) a += yS[s][e] * symW[e * DIM + d];
    red[s][d] = tanhf(a) * symu[d];
    __syncthreads();
    for (int o = 64; o; o >>= 1) {
        if (d < o) red[s][d] += red[s][d + o];
        __syncthreads();
    }
    if (tid < DIM) {
        float e0 = red[0][0], e1 = red[1][0], e2v = red[2][0], e3 = red[3][0];
        float m = fmaxf(fmaxf(e0, e1), fmaxf(e2v, e3));
        float a0 = expf(e0 - m), a1 = expf(e1 - m), a2 = expf(e2v - m), a3 = expf(e3 - m);
        float z = a0 + a1 + a2 + a3;
        float o = (a0 * yS[0][d] + a1 * yS[1][d] + a2 * yS[2][d] + a3 * yS[3][d]) / z;
        syn_out[b * DIM + d] = o;
    }
}

// ---------------- out = syn_out @ (z_tcm_raw/3)^T ----------------

__global__ __launch_bounds__(256) void final_gemm(
    const float* __restrict__ syn_o, const float* __restrict__ z_tcm,
    float* __restrict__ out)
{
    const float INV3 = 1.0f / 3.0f;
    int t0 = blockIdx.x * 64;
    int b0 = blockIdx.y * 16;
    int tid = threadIdx.x;
    __shared__ float zS[64][129];
    __shared__ float sS[16][129];
#pragma unroll
    for (int i = 0; i < 8; ++i) {
        int idx = i * 256 + tid;
        int r = idx >> 5, c4 = (idx & 31) * 4;
        int t = t0 + r;
        float4 v = make_float4(0.f, 0.f, 0.f, 0.f);
        if (t < NTCM) v = *(const float4*)&z_tcm[(long)t * DIM + c4];
        zS[r][c4 + 0] = v.x * INV3; zS[r][c4 + 1] = v.y * INV3;
        zS[r][c4 + 2] = v.z * INV3; zS[r][c4 + 3] = v.w * INV3;
    }
#pragma unroll
    for (int i = 0; i < 2; ++i) {
        int idx = i * 256 + tid;           // float4 idx over 16*32
        int r = idx >> 5, c4 = (idx & 31) * 4;
        float4 v = *(const float4*)&syn_o[(long)(b0 + r) * DIM + c4];
        sS[r][c4 + 0] = v.x; sS[r][c4 + 1] = v.y;
        sS[r][c4 + 2] = v.z; sS[r][c4 + 3] = v.w;
    }
    __syncthreads();
    int tt = tid & 63;
    int tbg = tid >> 6;
    float acc4[4] = {0.f, 0.f, 0.f, 0.f};
    for (int dd = 0; dd < DIM; ++dd) {
        float zv = zS[tt][dd];
#pragma unroll
        for (int i = 0; i < 4; ++i) acc4[i] += sS[tbg * 4 + i][dd] * zv;
    }
    int t = t0 + tt;
    if (t < NTCM) {
#pragma unroll
        for (int i = 0; i < 4; ++i)
            out[(long)(b0 + tbg * 4 + i) * NTCM + t] = acc4[i];
    }
}

// ---------------- launch ----------------

extern "C" void kernel_launch(void* const* d_in, const int* in_sizes, int n_in,
                              void* d_out, int out_size, void* d_ws, size_t ws_size,
                              hipStream_t stream)
{
    const float* x_dis  = (const float*)d_in[0];
    const float* x_syn  = (const float*)d_in[1];
    const float* x_tcm  = (const float*)d_in[2];
    const float* ds_Wsf = (const float*)d_in[3];
    const float* ds_bsf = (const float*)d_in[4];
    const float* ds_Wdf = (const float*)d_in[5];
    const float* ds_bdf = (const float*)d_in[6];
    const float* ds_semb = (const float*)d_in[7];
    const float* ds_demb = (const float*)d_in[8];
    const float* st_Wsf = (const float*)d_in[9];
    const float* st_bsf = (const float*)d_in[10];
    const float* st_Wdf = (const float*)d_in[11];
    const float* st_bdf = (const float*)d_in[12];
    const float* st_semb = (const float*)d_in[13];
    const float* st_demb = (const float*)d_in[14];
    const float* Wg  = (const float*)d_in[15];
    const float* bg  = (const float*)d_in[16];
    const float* att = (const float*)d_in[17];
    // d_in[18..20] (syn_W/b/u) and d_in[35] (syn_mask): dead code in reference
    const float* symW = (const float*)d_in[21];
    const float* symb = (const float*)d_in[22];
    const float* symu = (const float*)d_in[23];
    const float* Wv = (const float*)d_in[24];
    const float* bv = (const float*)d_in[25];
    const float* Wo = (const float*)d_in[26];
    const float* bo = (const float*)d_in[27];
    const float* Wl = (const float*)d_in[28];
    const float* bl = (const float*)d_in[29];
    const int* e_ds_src = (const int*)d_in[30];
    const int* e_ds_dst = (const int*)d_in[31];
    const int* e_st_src = (const int*)d_in[32];
    const int* e_st_dst = (const int*)d_in[33];
    const int* dis_mask = (const int*)d_in[34];

    char* p = (char*)d_ws;
    auto alloc = [&](size_t bytes) { char* r = p; p += (bytes + 255) & ~(size_t)255; return (void*)r; };

    // Region A: ek buffers for both graphs; 40,960,000 B == size of des,
    // so des reuses it after propagation.
    float* regA   = (float*)alloc((size_t)(2 * DSN + 2 * STN) * DIM * 4);
    float* ds_ek  = regA;
    float* ds_ek2 = regA + (long)DSN * DIM;
    float* st_ek  = regA + (long)2 * DSN * DIM;
    float* st_ek2 = regA + (long)2 * DSN * DIM + (long)STN * DIM;
    float* des    = regA;

    float* ds_acc = (float*)alloc((size_t)DSN * DIM * 4);
    float* st_acc = (float*)alloc((size_t)STN * DIM * 4);
    float* scores = (float*)alloc((size_t)NSYMV * NDIS * 4);
    int* ds_cnt = (int*)alloc((DSN + 1) * 4);
    int* ds_off = (int*)alloc((DSN + 1) * 4);
    int* ds_cur = (int*)alloc((DSN + 1) * 4);
    int* st_cnt = (int*)alloc((STN + 1) * 4);
    int* st_off = (int*)alloc((STN + 1) * 4);
    int* st_cur = (int*)alloc((STN + 1) * 4);
    float* ds_dinv = (float*)alloc(DSN * 4);
    float* st_dinv = (float*)alloc(STN * 4);
    int* ds_col = (int*)alloc((size_t)2 * NE1 * 4);
    int* st_col = (int*)alloc((size_t)2 * NE2 * 4);
    float* m_bs = (float*)alloc(BB * NSYMV * 4);
    float* z_bs = (float*)alloc(BB * NSYMV * 4);
    float* b_sym = (float*)alloc((size_t)NSYMV * BB * DIM * 4);
    float* syn_o = (float*)alloc((size_t)BB * DIM * 4);
    // partials OVERLAYS ds_acc: z_dis_raw (ds_acc) has no consumer after
    // gate_gemm, and bsym_partial is stream-ordered after it. 105 chunks *
    // 131072 B = 13.76 MB <= ds_acc's 14.34 MB.
    float* partials = ds_acc;

    // --- CSR build for both graphs ---
    hipMemsetAsync(ds_cnt, 0, DSN * 4, stream);
    hipMemsetAsync(st_cnt, 0, STN * 4, stream);
    count_edges<<<(NE1 + 255) / 256, 256, 0, stream>>>(e_ds_src, e_ds_dst, NE1, NDIS, ds_cnt);
    count_edges<<<(NE2 + 255) / 256, 256, 0, stream>>>(e_st_src, e_st_dst, NE2, NSYN, st_cnt);
    scan_offsets<<<1, 1024, 0, stream>>>(ds_cnt, ds_off, ds_cur, DSN);
    scan_offsets<<<1, 1024, 0, stream>>>(st_cnt, st_off, st_cur, STN);
    compute_dinv<<<(DSN + 255) / 256, 256, 0, stream>>>(ds_cnt, ds_dinv, DSN);
    compute_dinv<<<(STN + 255) / 256, 256, 0, stream>>>(st_cnt, st_dinv, STN);
    fill_csr<<<(NE1 + 255) / 256, 256, 0, stream>>>(e_ds_src, e_ds_dst, NE1, NDIS, ds_cur, ds_col);
    fill_csr<<<(NE2 + 255) / 256, 256, 0, stream>>>(e_st_src, e_st_dst, NE2, NSYN, st_cur, st_col);

    // --- e0 GEMMs (fused bias+emb; acc write skipped for dead halves) ---
    gemm_e0<<<dim3((NDIS + 63) / 64), 256, 0, stream>>>(x_dis, ds_Wsf, ds_bsf, ds_semb,
        ds_acc, ds_ek, NDIS, 384, 1, 1);
    gemm_e0<<<dim3((NSYN + 63) / 64), 256, 0, stream>>>(x_syn, ds_Wdf, ds_bdf, ds_demb,
        ds_acc + (long)NDIS * DIM, ds_ek + (long)NDIS * DIM, NSYN, 256, 1, 0);
    gemm_e0<<<dim3((NSYN + 63) / 64), 256, 0, stream>>>(x_syn, st_Wsf, st_bsf, st_semb,
        st_acc, st_ek, NSYN, 256, 1, 0);
    gemm_e0<<<dim3((NTCM + 63) / 64), 256, 0, stream>>>(x_tcm, st_Wdf, st_bdf, st_demb,
        st_acc + (long)NSYN * DIM, st_ek + (long)NSYN * DIM, NTCM, 103, 0, 1);

    // --- K=2 propagation (gather; only live node ranges; deterministic int accum) ---
    prop_step<<<(DSN + 3) / 4, 256, 0, stream>>>(ds_off, ds_col, ds_dinv, ds_ek, ds_ek2, ds_acc,
                                                 0, DSN, 0, NDIS, NDIS, DSN);
    prop_step<<<(NDIS + 3) / 4, 256, 0, stream>>>(ds_off, ds_col, ds_dinv, ds_ek2, ds_ek, ds_acc,
                                                  0, NDIS, 0, NDIS, 0, 0);
    prop_step<<<(STN + 3) / 4, 256, 0, stream>>>(st_off, st_col, st_dinv, st_ek, st_ek2, st_acc,
                                                 0, STN, NSYN, STN, 0, NSYN);
    prop_step<<<(NTCM + 3) / 4, 256, 0, stream>>>(st_off, st_col, st_dinv, st_ek2, st_ek, st_acc,
                                                  NSYN, STN, NSYN, STN, 0, 0);

    const float* z_dis_raw = ds_acc;                       // = 3*z_dis, scaled in consumers
    const float* z_tcm_raw = st_acc + (long)NSYN * DIM;    // = 3*z_tcm

    // --- gate/des + fused scores (overwrites region A: ek buffers dead now) ---
    gate_gemm<<<dim3((NDIS + 63) / 64, NSYMV), 256, 0, stream>>>(z_dis_raw, Wg, bg, att, des, scores);
    softmax_stats<<<BB, 256, 0, stream>>>(scores, dis_mask, m_bs, z_bs);
    // ds_acc (z_dis_raw) dead from here; partials reuses it
    bsym_partial<<<dim3(NBCHUNK, NSYMV), 256, 0, stream>>>(des, scores, dis_mask, m_bs, z_bs, partials);
    bsym_reduce<<<(NSYMV * BB * DIM) / 256, 256, 0, stream>>>(partials, b_sym);
    head_kernel<<<BB, 512, 0, stream>>>(b_sym, Wv, bv, Wo, bo, Wl, bl, symW, symb, symu, syn_o);
    final_gemm<<<dim3((NTCM + 63) / 64, BB / 16), 256, 0, stream>>>(syn_o, z_tcm_raw, (float*)d_out);
}

// Round 10
// 769.089 us; speedup vs baseline: 1.4045x; 1.2059x over previous
//
#include <hip/hip_runtime.h>
#include <hip/hip_bf16.h>
#include <math.h>

#define NDIS 20000
#define NSYN 8000
#define NTCM 4000
#define DIM  128
#define NSYMV 4
#define BB   64
#define NE1  400000
#define NE2  200000
#define DSN  (NDIS + NSYN)   // 28000
#define STN  (NSYN + NTCM)   // 12000

// b_sym chunking (atomic-free partials). BCHUNK=192 so the partials slab
// (NBCHUNK*4*64*128*4B = 13.76 MB) fits inside the dead ds_acc region (14.34 MB).
#define BCHUNK 192
#define NBCHUNK ((NDIS + BCHUNK - 1) / BCHUNK)   // 105

// fixed-point scale for deterministic (order-independent) prop accumulation
#define PROP_S    4194304.0f        // 2^22
#define PROP_INVS (1.0f / 4194304.0f)

// batched e0 GEMM: BM=32 rows/block, block ranges per problem
#define E0_B0 (NDIS / 32)              // 625
#define E0_B1 (NSYN / 32)              // 250
#define E0_B2 (NSYN / 32)              // 250
#define E0_B3 (NTCM / 32)              // 125
#define E0_GRID (E0_B0 + E0_B1 + E0_B2 + E0_B3)   // 1250

// ---------------- CSR build ----------------

__global__ void count_edges(const int* __restrict__ src, const int* __restrict__ dst,
                            int E, int n_src, int* __restrict__ cnt) {
    int i = blockIdx.x * blockDim.x + threadIdx.x;
    if (i < E) {
        atomicAdd(&cnt[src[i]], 1);
        atomicAdd(&cnt[dst[i] + n_src], 1);
    }
}

// single-block scan, wave-shuffle based
__global__ __launch_bounds__(1024) void scan_offsets(const int* __restrict__ cnt,
                                                     int* __restrict__ off,
                                                     int* __restrict__ cursor, int N) {
    __shared__ int wsum[16];
    __shared__ int carry_s;
    int tid = threadIdx.x;
    int lane = tid & 63, w = tid >> 6;
    if (tid == 0) carry_s = 0;
    __syncthreads();
    for (int base = 0; base < N; base += 1024) {
        int i = base + tid;
        int v = (i < N) ? cnt[i] : 0;
        int x = v;
#pragma unroll
        for (int d = 1; d < 64; d <<= 1) {
            int t = __shfl_up(x, d);
            if (lane >= d) x += t;
        }
        if (lane == 63) wsum[w] = x;
        __syncthreads();
        if (w == 0) {
            int y = (lane < 16) ? wsum[lane] : 0;
#pragma unroll
            for (int d = 1; d < 16; d <<= 1) {
                int t = __shfl_up(y, d);
                if (lane >= d) y += t;
            }
            if (lane < 16) wsum[lane] = y;
        }
        __syncthreads();
        int carry = carry_s;
        int wpre = (w > 0) ? wsum[w - 1] : 0;
        int excl = carry + wpre + x - v;
        if (i < N) { off[i] = excl; cursor[i] = excl; }
        __syncthreads();
        if (tid == 1023) carry_s = carry + wsum[15];
        __syncthreads();
    }
    if (tid == 0) off[N] = carry_s;
}

__global__ void compute_dinv(const int* __restrict__ cnt, float* __restrict__ dinv, int N) {
    int i = blockIdx.x * blockDim.x + threadIdx.x;
    if (i < N) {
        int c = cnt[i];
        dinv[i] = (c > 0) ? 1.0f / sqrtf((float)c) : 0.0f;
    }
}

__global__ void fill_csr(const int* __restrict__ src, const int* __restrict__ dst,
                         int E, int n_src, int* __restrict__ cursor, int* __restrict__ col) {
    int i = blockIdx.x * blockDim.x + threadIdx.x;
    if (i < E) {
        int a = src[i], b = dst[i] + n_src;
        int p = atomicAdd(&cursor[a], 1);
        col[p] = b;
        int q = atomicAdd(&cursor[b], 1);
        col[q] = a;
    }
}

// ---------------- batched e0: all four X@W+bias+emb GEMMs in one dispatch ----------------
// BM=32 rows/block, 256 threads, each thread 4 rows x 4 cols.

__global__ __launch_bounds__(256) void gemm_e0_all(
    const float* __restrict__ Xd, const float* __restrict__ Xs, const float* __restrict__ Xt,
    const float* __restrict__ W0, const float* __restrict__ c0, const float* __restrict__ m0,
    float* __restrict__ a0, float* __restrict__ k0p,
    const float* __restrict__ W1, const float* __restrict__ c1, const float* __restrict__ m1,
    float* __restrict__ k1p,
    const float* __restrict__ W2, const float* __restrict__ c2, const float* __restrict__ m2,
    float* __restrict__ k2p,
    const float* __restrict__ W3, const float* __restrict__ c3, const float* __restrict__ m3,
    float* __restrict__ a3, float* __restrict__ k3p)
{
    __shared__ float As[32][36];
    __shared__ float Bs[32][128];
    const int tid = threadIdx.x;
    const int blk = blockIdx.x;

    const float* X; const float* W; const float* bias; const float* emb;
    float* oacc; float* oek;
    int F, row0, wa, v4;
    if (blk < E0_B0) {
        X = Xd; W = W0; bias = c0; emb = m0; oacc = a0; oek = k0p;
        F = 384; wa = 1; v4 = 1; row0 = blk * 32;
    } else if (blk < E0_B0 + E0_B1) {
        X = Xs; W = W1; bias = c1; emb = m1; oacc = 0; oek = k1p;
        F = 256; wa = 0; v4 = 1; row0 = (blk - E0_B0) * 32;
    } else if (blk < E0_B0 + E0_B1 + E0_B2) {
        X = Xs; W = W2; bias = c2; emb = m2; oacc = 0; oek = k2p;
        F = 256; wa = 0; v4 = 1; row0 = (blk - E0_B0 - E0_B1) * 32;
    } else {
        X = Xt; W = W3; bias = c3; emb = m3; oacc = a3; oek = k3p;
        F = 103; wa = 1; v4 = 0; row0 = (blk - E0_B0 - E0_B1 - E0_B2) * 32;
    }

    const int tc = tid & 31;
    const int tr = tid >> 5;
    float acc[4][4];
#pragma unroll
    for (int i = 0; i < 4; ++i)
#pragma unroll
        for (int j = 0; j < 4; ++j) acc[i][j] = 0.f;

    for (int k0 = 0; k0 < F; k0 += 32) {
        {   // A tile 32x32: each thread one float4
            int ar = tid >> 3;
            int ac = (tid & 7) * 4;
            int gr = row0 + ar;
            if (v4) {
                *(float4*)&As[ar][ac] = *(const float4*)&X[(long)gr * F + k0 + ac];
            } else {
#pragma unroll
                for (int j = 0; j < 4; ++j) {
                    int k = k0 + ac + j;
                    As[ar][ac + j] = (k < F) ? X[(long)gr * F + k] : 0.f;
                }
            }
        }
        {   // B tile 32x128
            int brow = tid >> 5;
            int bc = (tid & 31) * 4;
#pragma unroll
            for (int h = 0; h < 4; ++h) {
                int r = brow + h * 8;
                int k = k0 + r;
                float4 v = make_float4(0.f, 0.f, 0.f, 0.f);
                if (k < F) v = *(const float4*)&W[(long)k * DIM + bc];
                *(float4*)&Bs[r][bc] = v;
            }
        }
        __syncthreads();
#pragma unroll
        for (int kk = 0; kk < 32; kk += 4) {
            float4 a4[4];
#pragma unroll
            for (int i = 0; i < 4; ++i) a4[i] = *(const float4*)&As[tr * 4 + i][kk];
            float4 b0 = *(const float4*)&Bs[kk + 0][tc * 4];
            float4 b1 = *(const float4*)&Bs[kk + 1][tc * 4];
            float4 b2 = *(const float4*)&Bs[kk + 2][tc * 4];
            float4 b3 = *(const float4*)&Bs[kk + 3][tc * 4];
#pragma unroll
            for (int i = 0; i < 4; ++i) {
                acc[i][0] += a4[i].x * b0.x + a4[i].y * b1.x + a4[i].z * b2.x + a4[i].w * b3.x;
                acc[i][1] += a4[i].x * b0.y + a4[i].y * b1.y + a4[i].z * b2.y + a4[i].w * b3.y;
                acc[i][2] += a4[i].x * b0.z + a4[i].y * b1.z + a4[i].z * b2.z + a4[i].w * b3.z;
                acc[i][3] += a4[i].x * b0.w + a4[i].y * b1.w + a4[i].z * b2.w + a4[i].w * b3.w;
            }
        }
        __syncthreads();
    }
    int c = tc * 4;
    float4 bi = *(const float4*)&bias[c];
#pragma unroll
    for (int i = 0; i < 4; ++i) {
        int r = row0 + tr * 4 + i;
        float4 e = *(const float4*)&emb[(long)r * DIM + c];
        float4 v;
        v.x = acc[i][0] + bi.x + e.x;
        v.y = acc[i][1] + bi.y + e.y;
        v.z = acc[i][2] + bi.z + e.z;
        v.w = acc[i][3] + bi.w + e.w;
        if (wa) *(float4*)&oacc[(long)r * DIM + c] = v;
        *(float4*)&oek[(long)r * DIM + c] = v;
    }
}

// ---------------- LightGCN propagation: gather per node (wave per node) ----------------
// Deterministic: per-term fixed-point quantization -> integer sum is
// order-independent, so the nondeterministic CSR fill order doesn't matter.

__global__ __launch_bounds__(256) void prop_step(
    const int* __restrict__ off, const int* __restrict__ col,
    const float* __restrict__ dinv, const float* __restrict__ ek,
    float* __restrict__ ek2, float* __restrict__ acc,
    int n0, int n1, int acc_lo, int acc_hi, int ek_lo, int ek_hi)
{
    int wid = n0 + ((blockIdx.x * blockDim.x + threadIdx.x) >> 6);
    int lane = threadIdx.x & 63;
    if (wid >= n1) return;
    int beg = off[wid], end = off[wid + 1];
    float dn = dinv[wid];
    long long sx = 0, sy = 0;
    int j = beg;
    for (; j + 4 <= end; j += 4) {
        int c0 = col[j + 0], c1 = col[j + 1], c2 = col[j + 2], c3 = col[j + 3];
        float w0 = dinv[c0] * PROP_S, w1 = dinv[c1] * PROP_S;
        float w2 = dinv[c2] * PROP_S, w3 = dinv[c3] * PROP_S;
        float2 v0 = *(const float2*)&ek[(long)c0 * DIM + lane * 2];
        float2 v1 = *(const float2*)&ek[(long)c1 * DIM + lane * 2];
        float2 v2 = *(const float2*)&ek[(long)c2 * DIM + lane * 2];
        float2 v3 = *(const float2*)&ek[(long)c3 * DIM + lane * 2];
        sx += (long long)__float2int_rn(w0 * v0.x) + (long long)__float2int_rn(w1 * v1.x)
            + (long long)__float2int_rn(w2 * v2.x) + (long long)__float2int_rn(w3 * v3.x);
        sy += (long long)__float2int_rn(w0 * v0.y) + (long long)__float2int_rn(w1 * v1.y)
            + (long long)__float2int_rn(w2 * v2.y) + (long long)__float2int_rn(w3 * v3.y);
    }
    for (; j < end; ++j) {
        int c = col[j];
        float w = dinv[c] * PROP_S;
        float2 v = *(const float2*)&ek[(long)c * DIM + lane * 2];
        sx += (long long)__float2int_rn(w * v.x);
        sy += (long long)__float2int_rn(w * v.y);
    }
    float ax = (float)sx * PROP_INVS * dn;
    float ay = (float)sy * PROP_INVS * dn;
    if (wid >= ek_lo && wid < ek_hi) {
        float2* e2p = (float2*)&ek2[(long)wid * DIM + lane * 2];
        e2p->x = ax; e2p->y = ay;
    }
    if (wid >= acc_lo && wid < acc_hi) {
        float2* ap = (float2*)&acc[(long)wid * DIM + lane * 2];
        float2 o = *ap;
        o.x += ax; o.y += ay;
        *ap = o;
    }
}

// ---------------- gate + des + fused scores ----------------
// des[s,n,:] = (z/3) * sigmoid((zraw@Wg[s])/3 + bg[s]);  scores[s,n] = des . att

__global__ __launch_bounds__(256) void gate_gemm(
    const float* __restrict__ X, const float* __restrict__ Wg,
    const float* __restrict__ bg, const float* __restrict__ att,
    float* __restrict__ des, float* __restrict__ scores)
{
    const float INV3 = 1.0f / 3.0f;
    int s = blockIdx.y;
    const float* Wm = Wg + (long)s * DIM * DIM;
    __shared__ float As[64][36];
    __shared__ float Bs[32][128];
    const int tid = threadIdx.x;
    const int row0 = blockIdx.x * 64;
    const int tc = tid & 31;
    const int tr = tid >> 5;
    float acc[8][4];
#pragma unroll
    for (int i = 0; i < 8; ++i)
#pragma unroll
        for (int j = 0; j < 4; ++j) acc[i][j] = 0.f;

    for (int k0 = 0; k0 < DIM; k0 += 32) {
        {
            int ar = tid >> 3;
            int ac = (tid & 7) * 4;
#pragma unroll
            for (int h = 0; h < 2; ++h) {
                int r = ar + h * 32;
                int gr = row0 + r;
                float4 v = make_float4(0.f, 0.f, 0.f, 0.f);
                if (gr < NDIS) v = *(const float4*)&X[(long)gr * DIM + k0 + ac];
                *(float4*)&As[r][ac] = v;
            }
        }
        {
            int brow = tid >> 5;
            int bc = (tid & 31) * 4;
#pragma unroll
            for (int h = 0; h < 4; ++h) {
                int r = brow + h * 8;
                *(float4*)&Bs[r][bc] = *(const float4*)&Wm[(long)(k0 + r) * DIM + bc];
            }
        }
        __syncthreads();
#pragma unroll
        for (int kk = 0; kk < 32; kk += 4) {
            float4 a4[8];
#pragma unroll
            for (int i = 0; i < 8; ++i) a4[i] = *(const float4*)&As[tr * 8 + i][kk];
            float4 b0 = *(const float4*)&Bs[kk + 0][tc * 4];
            float4 b1 = *(const float4*)&Bs[kk + 1][tc * 4];
            float4 b2 = *(const float4*)&Bs[kk + 2][tc * 4];
            float4 b3 = *(const float4*)&Bs[kk + 3][tc * 4];
#pragma unroll
            for (int i = 0; i < 8; ++i) {
                acc[i][0] += a4[i].x * b0.x + a4[i].y * b1.x + a4[i].z * b2.x + a4[i].w * b3.x;
                acc[i][1] += a4[i].x * b0.y + a4[i].y * b1.y + a4[i].z * b2.y + a4[i].w * b3.y;
                acc[i][2] += a4[i].x * b0.z + a4[i].y * b1.z + a4[i].z * b2.z + a4[i].w * b3.z;
                acc[i][3] += a4[i].x * b0.w + a4[i].y * b1.w + a4[i].z * b2.w + a4[i].w * b3.w;
            }
        }
        __syncthreads();
    }
    int c = tc * 4;
    float4 av = *(const float4*)&att[c];
    float4 bi = *(const float4*)&bg[s * DIM + c];
#pragma unroll
    for (int i = 0; i < 8; ++i) {
        int r = row0 + tr * 8 + i;
        float4 v = make_float4(0.f, 0.f, 0.f, 0.f);
        if (r < NDIS) {
            float4 z = *(const float4*)&X[(long)r * DIM + c];
            v.x = z.x * INV3 / (1.0f + expf(-(acc[i][0] * INV3 + bi.x)));
            v.y = z.y * INV3 / (1.0f + expf(-(acc[i][1] * INV3 + bi.y)));
            v.z = z.z * INV3 / (1.0f + expf(-(acc[i][2] * INV3 + bi.z)));
            v.w = z.w * INV3 / (1.0f + expf(-(acc[i][3] * INV3 + bi.w)));
            *(float4*)&des[((long)s * NDIS + r) * DIM + c] = v;
        }
        // fused score: dot(des_row, att) reduced across the 32 tc lanes (half-wave)
        float sd = v.x * av.x + v.y * av.y + v.z * av.z + v.w * av.w;
#pragma unroll
        for (int o2 = 1; o2 < 32; o2 <<= 1) sd += __shfl_xor(sd, o2);
        if (tc == 0 && r < NDIS) scores[(long)s * NDIS + r] = sd;
    }
}

// ---------------- masked softmax stats per b (all 4 views in one pass) ----------------

__global__ __launch_bounds__(256) void softmax_stats(
    const float* __restrict__ scores, const int* __restrict__ dm,
    float* __restrict__ m_out, float* __restrict__ z_out)
{
    int b = blockIdx.x, tid = threadIdx.x;
    const int* mk = dm + (long)b * NDIS;
    __shared__ float red[NSYMV][256];
    float mloc[NSYMV] = {-1e9f, -1e9f, -1e9f, -1e9f};
    for (int n = tid; n < NDIS; n += 256) {
        if (mk[n]) {
#pragma unroll
            for (int s = 0; s < NSYMV; ++s)
                mloc[s] = fmaxf(mloc[s], scores[(long)s * NDIS + n]);
        }
    }
#pragma unroll
    for (int s = 0; s < NSYMV; ++s) red[s][tid] = mloc[s];
    __syncthreads();
    for (int o = 128; o; o >>= 1) {
        if (tid < o) {
#pragma unroll
            for (int s = 0; s < NSYMV; ++s)
                red[s][tid] = fmaxf(red[s][tid], red[s][tid + o]);
        }
        __syncthreads();
    }
    float m[NSYMV];
#pragma unroll
    for (int s = 0; s < NSYMV; ++s) m[s] = red[s][0];
    __syncthreads();
    float zloc[NSYMV] = {0.f, 0.f, 0.f, 0.f};
    for (int n = tid; n < NDIS; n += 256) {
        if (mk[n]) {
#pragma unroll
            for (int s = 0; s < NSYMV; ++s)
                zloc[s] += expf(scores[(long)s * NDIS + n] - m[s]);
        }
    }
#pragma unroll
    for (int s = 0; s < NSYMV; ++s) red[s][tid] = zloc[s];
    __syncthreads();
    for (int o = 128; o; o >>= 1) {
        if (tid < o) {
#pragma unroll
            for (int s = 0; s < NSYMV; ++s)
                red[s][tid] += red[s][tid + o];
        }
        __syncthreads();
    }
    if (tid < NSYMV) {
        m_out[b * NSYMV + tid] = m[tid];
        z_out[b * NSYMV + tid] = red[tid][0];
    }
}

// ---------------- b_sym partials: per (s, BCHUNK-row chunk), all 64 b; NO atomics ----------------
// partials layout: [chunk][s][b][d]

__global__ __launch_bounds__(256) void bsym_partial(
    const float* __restrict__ des, const float* __restrict__ scores,
    const int* __restrict__ dm, const float* __restrict__ m_in,
    const float* __restrict__ z_in, float* __restrict__ partials)
{
    int s = blockIdx.y;
    int chunk = blockIdx.x;
    int tid = threadIdx.x;
    __shared__ float desS[64][128];
    __shared__ float wS[64][65];   // [b][n']
    const int tb = tid & 7;
    const int td = tid >> 3;
    float acc[8][4];
#pragma unroll
    for (int i = 0; i < 8; ++i)
#pragma unroll
        for (int j = 0; j < 4; ++j) acc[i][j] = 0.f;

    for (int sub = 0; sub < BCHUNK / 64; ++sub) {
        int n0 = chunk * BCHUNK + sub * 64;
#pragma unroll
        for (int i = 0; i < 8; ++i) {
            int idx = i * 256 + tid;           // float4 index over 64*32
            int r = idx >> 5, c4 = (idx & 31) * 4;
            int n = n0 + r;
            float4 v = make_float4(0.f, 0.f, 0.f, 0.f);
            if (n < NDIS) v = *(const float4*)&des[((long)s * NDIS + n) * DIM + c4];
            *(float4*)&desS[r][c4] = v;
        }
        {
            int b = tid >> 2;
            int q = tid & 3;
            float m = m_in[b * NSYMV + s];
            float Z = z_in[b * NSYMV + s];
#pragma unroll
            for (int h = 0; h < 16; ++h) {
                int nn = q * 16 + h;
                int n = n0 + nn;
                float w = 0.f;
                if (n < NDIS && dm[(long)b * NDIS + n])
                    w = expf(scores[(long)s * NDIS + n] - m) / Z;
                wS[b][nn] = w;
            }
        }
        __syncthreads();
        for (int nn = 0; nn < 64; ++nn) {
            float4 dv = *(const float4*)&desS[nn][td * 4];
#pragma unroll
            for (int i = 0; i < 8; ++i) {
                float w = wS[tb * 8 + i][nn];
                acc[i][0] += w * dv.x; acc[i][1] += w * dv.y;
                acc[i][2] += w * dv.z; acc[i][3] += w * dv.w;
            }
        }
        __syncthreads();
    }
    float* pp = partials + ((long)chunk * NSYMV + s) * (BB * DIM);
#pragma unroll
    for (int i = 0; i < 8; ++i) {
        int b = tb * 8 + i;
        float4 v;
        v.x = acc[i][0]; v.y = acc[i][1]; v.z = acc[i][2]; v.w = acc[i][3];
        *(float4*)&pp[b * DIM + td * 4] = v;
    }
}

// ---------------- reduce partials over chunks (fixed order -> deterministic) ----------------
// b_sym layout: [s][b][d]

__global__ __launch_bounds__(256) void bsym_reduce(
    const float* __restrict__ partials, float* __restrict__ b_sym)
{
    int o = blockIdx.x * 256 + threadIdx.x;   // over NSYMV*BB*DIM = 32768
    float a = 0.f;
    for (int c = 0; c < NBCHUNK; ++c)
        a += partials[(long)c * (NSYMV * BB * DIM) + o];
    b_sym[o] = a;
}

// ---------------- tiny head: v->o->sym_syn->a2->syn_out, block per b, (s,d) parallel ----------------

__global__ __launch_bounds__(512) void head_kernel(
    const float* __restrict__ b_sym,   // [s][b][d]
    const float* __restrict__ Wv, const float* __restrict__ bv,
    const float* __restrict__ Wo, const float* __restrict__ bo,
    const float* __restrict__ Wl, const float* __restrict__ bl,
    const float* __restrict__ symW, const float* __restrict__ symb,
    const float* __restrict__ symu, float* __restrict__ syn_out)
{
    int b = blockIdx.x;
    int tid = threadIdx.x;
    int s = tid >> 7;
    int d = tid & 127;
    __shared__ float xS[NSYMV][DIM];
    __shared__ float yS[NSYMV][DIM];
    __shared__ float red[NSYMV][DIM];
    xS[s][d] = b_sym[((long)s * BB + b) * DIM + d];
    __syncthreads();
    // v = b_sym @ Wv + bv
    float a = bv[d];
    for (int e = 0; e < DIM; ++e) a += xS[s][e] * Wv[e * DIM + d];
    yS[s][d] = a;
    __syncthreads();
    // o = v @ Wo + bo
    a = bo[d];
    for (int e = 0; e < DIM; ++e) a += yS[s][e] * Wo[e * DIM + d];
    xS[s][d] = a;
    __syncthreads();
    // sym_syn = o + o @ Wl[s] + bl[s]
    a = xS[s][d] + bl[s * DIM + d];
    {
        const float* Wls = Wl + (long)s * DIM * DIM;
        for (int e = 0; e < DIM; ++e) a += xS[s][e] * Wls[e * DIM + d];
    }
    yS[s][d] = a;
    __syncthreads();
    // e2 = tanh(sym_syn @ symW + symb) . symu
    a = symb[d];
    for (int e = 0; e < DIM; ++e) a += yS[s][e] * symW[e * DIM + d];
    red[s][d] = tanhf(a) * symu[d];
    __syncthreads();
    for (int o = 64; o; o >>= 1) {
        if (d < o) red[s][d] += red[s][d + o];
        __syncthreads();
    }
    if (tid < DIM) {
        float e0 = red[0][0], e1 = red[1][0], e2v = red[2][0], e3 = red[3][0];
        float m = fmaxf(fmaxf(e0, e1), fmaxf(e2v, e3));
        float a0 = expf(e0 - m), a1 = expf(e1 - m), a2 = expf(e2v - m), a3 = expf(e3 - m);
        float z = a0 + a1 + a2 + a3;
        float o = (a0 * yS[0][d] + a1 * yS[1][d] + a2 * yS[2][d] + a3 * yS[3][d]) / z;
        syn_out[b * DIM + d] = o;
    }
}

// ---------------- out = syn_out @ (z_tcm_raw/3)^T ----------------

__global__ __launch_bounds__(256) void final_gemm(
    const float* __restrict__ syn_o, const float* __restrict__ z_tcm,
    float* __restrict__ out)
{
    const float INV3 = 1.0f / 3.0f;
    int t0 = blockIdx.x * 64;
    int b0 = blockIdx.y * 16;
    int tid = threadIdx.x;
    __shared__ float zS[64][129];
    __shared__ float sS[16][129];
#pragma unroll
    for (int i = 0; i < 8; ++i) {
        int idx = i * 256 + tid;
        int r = idx >> 5, c4 = (idx & 31) * 4;
        int t = t0 + r;
        float4 v = make_float4(0.f, 0.f, 0.f, 0.f);
        if (t < NTCM) v = *(const float4*)&z_tcm[(long)t * DIM + c4];
        zS[r][c4 + 0] = v.x * INV3; zS[r][c4 + 1] = v.y * INV3;
        zS[r][c4 + 2] = v.z * INV3; zS[r][c4 + 3] = v.w * INV3;
    }
#pragma unroll
    for (int i = 0; i < 2; ++i) {
        int idx = i * 256 + tid;           // float4 idx over 16*32
        int r = idx >> 5, c4 = (idx & 31) * 4;
        float4 v = *(const float4*)&syn_o[(long)(b0 + r) * DIM + c4];
        sS[r][c4 + 0] = v.x; sS[r][c4 + 1] = v.y;
        sS[r][c4 + 2] = v.z; sS[r][c4 + 3] = v.w;
    }
    __syncthreads();
    int tt = tid & 63;
    int tbg = tid >> 6;
    float acc4[4] = {0.f, 0.f, 0.f, 0.f};
    for (int dd = 0; dd < DIM; ++dd) {
        float zv = zS[tt][dd];
#pragma unroll
        for (int i = 0; i < 4; ++i) acc4[i] += sS[tbg * 4 + i][dd] * zv;
    }
    int t = t0 + tt;
    if (t < NTCM) {
#pragma unroll
        for (int i = 0; i < 4; ++i)
            out[(long)(b0 + tbg * 4 + i) * NTCM + t] = acc4[i];
    }
}

// ---------------- launch ----------------

extern "C" void kernel_launch(void* const* d_in, const int* in_sizes, int n_in,
                              void* d_out, int out_size, void* d_ws, size_t ws_size,
                              hipStream_t stream)
{
    const float* x_dis  = (const float*)d_in[0];
    const float* x_syn  = (const float*)d_in[1];
    const float* x_tcm  = (const float*)d_in[2];
    const float* ds_Wsf = (const float*)d_in[3];
    const float* ds_bsf = (const float*)d_in[4];
    const float* ds_Wdf = (const float*)d_in[5];
    const float* ds_bdf = (const float*)d_in[6];
    const float* ds_semb = (const float*)d_in[7];
    const float* ds_demb = (const float*)d_in[8];
    const float* st_Wsf = (const float*)d_in[9];
    const float* st_bsf = (const float*)d_in[10];
    const float* st_Wdf = (const float*)d_in[11];
    const float* st_bdf = (const float*)d_in[12];
    const float* st_semb = (const float*)d_in[13];
    const float* st_demb = (const float*)d_in[14];
    const float* Wg  = (const float*)d_in[15];
    const float* bg  = (const float*)d_in[16];
    const float* att = (const float*)d_in[17];
    // d_in[18..20] (syn_W/b/u) and d_in[35] (syn_mask): dead code in reference
    const float* symW = (const float*)d_in[21];
    const float* symb = (const float*)d_in[22];
    const float* symu = (const float*)d_in[23];
    const float* Wv = (const float*)d_in[24];
    const float* bv = (const float*)d_in[25];
    const float* Wo = (const float*)d_in[26];
    const float* bo = (const float*)d_in[27];
    const float* Wl = (const float*)d_in[28];
    const float* bl = (const float*)d_in[29];
    const int* e_ds_src = (const int*)d_in[30];
    const int* e_ds_dst = (const int*)d_in[31];
    const int* e_st_src = (const int*)d_in[32];
    const int* e_st_dst = (const int*)d_in[33];
    const int* dis_mask = (const int*)d_in[34];

    char* p = (char*)d_ws;
    auto alloc = [&](size_t bytes) { char* r = p; p += (bytes + 255) & ~(size_t)255; return (void*)r; };

    // Region A: ek buffers for both graphs; 40,960,000 B == size of des,
    // so des reuses it after propagation.
    float* regA   = (float*)alloc((size_t)(2 * DSN + 2 * STN) * DIM * 4);
    float* ds_ek  = regA;
    float* ds_ek2 = regA + (long)DSN * DIM;
    float* st_ek  = regA + (long)2 * DSN * DIM;
    float* st_ek2 = regA + (long)2 * DSN * DIM + (long)STN * DIM;
    float* des    = regA;

    float* ds_acc = (float*)alloc((size_t)DSN * DIM * 4);
    float* st_acc = (float*)alloc((size_t)STN * DIM * 4);
    float* scores = (float*)alloc((size_t)NSYMV * NDIS * 4);
    int* ds_cnt = (int*)alloc((DSN + 1) * 4);
    int* ds_off = (int*)alloc((DSN + 1) * 4);
    int* ds_cur = (int*)alloc((DSN + 1) * 4);
    int* st_cnt = (int*)alloc((STN + 1) * 4);
    int* st_off = (int*)alloc((STN + 1) * 4);
    int* st_cur = (int*)alloc((STN + 1) * 4);
    float* ds_dinv = (float*)alloc(DSN * 4);
    float* st_dinv = (float*)alloc(STN * 4);
    int* ds_col = (int*)alloc((size_t)2 * NE1 * 4);
    int* st_col = (int*)alloc((size_t)2 * NE2 * 4);
    float* m_bs = (float*)alloc(BB * NSYMV * 4);
    float* z_bs = (float*)alloc(BB * NSYMV * 4);
    float* b_sym = (float*)alloc((size_t)NSYMV * BB * DIM * 4);
    float* syn_o = (float*)alloc((size_t)BB * DIM * 4);
    // partials OVERLAYS ds_acc: z_dis_raw (ds_acc) has no consumer after
    // gate_gemm, and bsym_partial is stream-ordered after it. 105 chunks *
    // 131072 B = 13.76 MB <= ds_acc's 14.34 MB.
    float* partials = ds_acc;

    // --- CSR build for both graphs ---
    hipMemsetAsync(ds_cnt, 0, DSN * 4, stream);
    hipMemsetAsync(st_cnt, 0, STN * 4, stream);
    count_edges<<<(NE1 + 255) / 256, 256, 0, stream>>>(e_ds_src, e_ds_dst, NE1, NDIS, ds_cnt);
    count_edges<<<(NE2 + 255) / 256, 256, 0, stream>>>(e_st_src, e_st_dst, NE2, NSYN, st_cnt);
    scan_offsets<<<1, 1024, 0, stream>>>(ds_cnt, ds_off, ds_cur, DSN);
    scan_offsets<<<1, 1024, 0, stream>>>(st_cnt, st_off, st_cur, STN);
    compute_dinv<<<(DSN + 255) / 256, 256, 0, stream>>>(ds_cnt, ds_dinv, DSN);
    compute_dinv<<<(STN + 255) / 256, 256, 0, stream>>>(st_cnt, st_dinv, STN);
    fill_csr<<<(NE1 + 255) / 256, 256, 0, stream>>>(e_ds_src, e_ds_dst, NE1, NDIS, ds_cur, ds_col);
    fill_csr<<<(NE2 + 255) / 256, 256, 0, stream>>>(e_st_src, e_st_dst, NE2, NSYN, st_cur, st_col);

    // --- all four e0 GEMMs in ONE dispatch (1250 blocks; fused bias+emb) ---
    gemm_e0_all<<<E0_GRID, 256, 0, stream>>>(
        x_dis, x_syn, x_tcm,
        ds_Wsf, ds_bsf, ds_semb, ds_acc, ds_ek,
        ds_Wdf, ds_bdf, ds_demb, ds_ek + (long)NDIS * DIM,
        st_Wsf, st_bsf, st_semb, st_ek,
        st_Wdf, st_bdf, st_demb, st_acc + (long)NSYN * DIM, st_ek + (long)NSYN * DIM);

    // --- K=2 propagation (gather; only live node ranges; deterministic int accum) ---
    prop_step<<<(DSN + 3) / 4, 256, 0, stream>>>(ds_off, ds_col, ds_dinv, ds_ek, ds_ek2, ds_acc,
                                                 0, DSN, 0, NDIS, NDIS, DSN);
    prop_step<<<(NDIS + 3) / 4, 256, 0, stream>>>(ds_off, ds_col, ds_dinv, ds_ek2, ds_ek, ds_acc,
                                                  0, NDIS, 0, NDIS, 0, 0);
    prop_step<<<(STN + 3) / 4, 256, 0, stream>>>(st_off, st_col, st_dinv, st_ek, st_ek2, st_acc,
                                                 0, STN, NSYN, STN, 0, NSYN);
    prop_step<<<(NTCM + 3) / 4, 256, 0, stream>>>(st_off, st_col, st_dinv, st_ek2, st_ek, st_acc,
                                                  NSYN, STN, NSYN, STN, 0, 0);

    const float* z_dis_raw = ds_acc;                       // = 3*z_dis, scaled in consumers
    const float* z_tcm_raw = st_acc + (long)NSYN * DIM;    // = 3*z_tcm

    // --- gate/des + fused scores (overwrites region A: ek buffers dead now) ---
    gate_gemm<<<dim3((NDIS + 63) / 64, NSYMV), 256, 0, stream>>>(z_dis_raw, Wg, bg, att, des, scores);
    softmax_stats<<<BB, 256, 0, stream>>>(scores, dis_mask, m_bs, z_bs);
    // ds_acc (z_dis_raw) dead from here; partials reuses it
    bsym_partial<<<dim3(NBCHUNK, NSYMV), 256, 0, stream>>>(des, scores, dis_mask, m_bs, z_bs, partials);
    bsym_reduce<<<(NSYMV * BB * DIM) / 256, 256, 0, stream>>>(partials, b_sym);
    head_kernel<<<BB, 512, 0, stream>>>(b_sym, Wv, bv, Wo, bo, Wl, bl, symW, symb, symu, syn_o);
    final_gemm<<<dim3((NTCM + 63) / 64, BB / 16), 256, 0, stream>>>(syn_o, z_tcm_raw, (float*)d_out);
}